// Round 9
// baseline (324.609 us; speedup 1.0000x reference)
//
#include <hip/hip_runtime.h>

typedef __bf16 bf16x8 __attribute__((ext_vector_type(8)));
typedef float f32x4 __attribute__((ext_vector_type(4)));

#define DEVI static __device__ __forceinline__
#define CHUNK 4096
#define SCH 8192

DEVI unsigned short f2bf(float f){
  unsigned int x = __builtin_bit_cast(unsigned int, f);
  x = (x + 0x7fffu + ((x >> 16) & 1u)) >> 16;
  return (unsigned short)x;
}
DEVI unsigned int packbf2(float a, float b){
  return (unsigned int)f2bf(a) | ((unsigned int)f2bf(b) << 16);
}
DEVI float bflo(unsigned int u){ return __builtin_bit_cast(float, u << 16); }
DEVI float bfhi(unsigned int u){ return __builtin_bit_cast(float, u & 0xffff0000u); }

__global__ void k_zero(int* __restrict__ p, int n){
  int i = blockIdx.x*256 + threadIdx.x;
  if (i < n) p[i] = 0;
}

// ---- two-level bucketed CSR build ----
// fine bucket = 256 consecutive dst nodes (391); coarse = 2048 nodes (49).

__global__ __launch_bounds__(256) void kb_hist(const int* __restrict__ dst,
    int* __restrict__ bucketCnt, int E, int NB){
  __shared__ int h[2048];
  for (int i=threadIdx.x;i<NB;i+=256) h[i]=0;
  __syncthreads();
  int base = blockIdx.x*CHUNK;
  int lim = base+CHUNK < E ? base+CHUNK : E;
  for (int i = base+threadIdx.x; i < lim; i += 256)
    atomicAdd(&h[dst[i]>>8], 1);
  __syncthreads();
  for (int i=threadIdx.x;i<NB;i+=256)
    if (h[i]) atomicAdd(&bucketCnt[i], h[i]);
}

// one block: fine scan (bOff/bCur) + coarse cursors (cCur[c]=bOff[c*8])
__global__ __launch_bounds__(256) void kb_scan(const int* __restrict__ bucketCnt,
    int* __restrict__ bucketOff, int* __restrict__ bucketCur,
    int* __restrict__ cCur, int NB, int NBC){
  __shared__ int sh[256];
  int t = threadIdx.x;
  int per = (NB+255)/256;
  int vals[8];
  int lsum = 0;
  for (int j=0;j<per;j++){
    int i = t*per+j;
    int v = (i<NB) ? bucketCnt[i] : 0;
    vals[j]=v; lsum+=v;
  }
  sh[t]=lsum; __syncthreads();
  for (int off=1; off<256; off<<=1){
    int x = (t>=off) ? sh[t-off] : 0;
    __syncthreads();
    sh[t] += x;
    __syncthreads();
  }
  int run = sh[t]-lsum;
  for (int j=0;j<per;j++){
    int i = t*per+j;
    if (i<NB){ bucketOff[i]=run; bucketCur[i]=run; }
    run += vals[j];
  }
  if (t==255) bucketOff[NB]=run;
  __syncthreads();
  for (int c=t;c<NBC;c+=256){
    int f = c*8;
    cCur[c] = bucketOff[f < NB ? f : NB];
  }
}

// pass 1: chunked LDS-histogram scatter by coarse bucket (dst>>11)
__global__ __launch_bounds__(512) void kb_scat1(const int* __restrict__ src,
    const int* __restrict__ dst, int* __restrict__ cur,
    int* __restrict__ srco, int* __restrict__ dsto, int E, int NBK){
  __shared__ int h[64];
  __shared__ int baseSh[64];
  int t = threadIdx.x;
  if (t < NBK){ h[t]=0; }
  __syncthreads();
  int base = blockIdx.x*SCH;
  int lim = base+SCH < E ? base+SCH : E;
  for (int i = base+t; i < lim; i += 512)
    atomicAdd(&h[dst[i]>>11], 1);
  __syncthreads();
  if (t < NBK){
    int c = h[t];
    baseSh[t] = c ? atomicAdd(&cur[t], c) : 0;
    h[t] = 0;
  }
  __syncthreads();
  for (int i = base+t; i < lim; i += 512){
    int d = dst[i];
    int b = d>>11;
    int r = atomicAdd(&h[b], 1);
    int p = baseSh[b] + r;
    srco[p] = src[i];
    dsto[p] = d;
  }
}

// pass 2: scatter by fine bucket (dst>>8); writes PACKED (src<<8)|(dst&255)
__global__ __launch_bounds__(512) void kb_scat2(const int* __restrict__ src,
    const int* __restrict__ dst, int* __restrict__ cur,
    int* __restrict__ pk, int E, int NBK){
  __shared__ int h[2048];
  __shared__ int baseSh[2048];
  int t = threadIdx.x;
  for (int i=t;i<NBK;i+=512) h[i]=0;
  __syncthreads();
  int base = blockIdx.x*SCH;
  int lim = base+SCH < E ? base+SCH : E;
  for (int i = base+t; i < lim; i += 512)
    atomicAdd(&h[dst[i]>>8], 1);
  __syncthreads();
  for (int i=t;i<NBK;i+=512){
    int c = h[i];
    baseSh[i] = c ? atomicAdd(&cur[i], c) : 0;
    h[i] = 0;
  }
  __syncthreads();
  for (int i = base+t; i < lim; i += 512){
    int d = dst[i];
    int b = d>>8;
    int r = atomicAdd(&h[b], 1);
    int p = baseSh[b] + r;
    pk[p] = (src[i]<<8) | (d&255);
  }
}

// Pack row-major fp32 W[K][N] into MFMA B-fragment order:
// frag (ks, cf), lane l, elem j  <-  W[ks*32 + (l>>4)*8 + j][cf*16 + (l&15)]
DEVI void packW(const float* __restrict__ W, unsigned short* __restrict__ Wp,
                int idx, int N, int NF){
  int l = idx & 63;
  int frag = idx >> 6;
  int cf = frag % NF;
  int ks = frag / NF;
  int kbase = ks*32 + (l>>4)*8;
  int col = cf*16 + (l&15);
  unsigned short* dp = Wp + (size_t)idx*8;
  #pragma unroll
  for (int j=0;j<8;j++) dp[j] = f2bf(W[(size_t)(kbase+j)*N + col]);
}

// Fused per-bucket: count -> LDS scan -> rp/dinv -> rank & write csr -> cvt
// this bucket's x rows into xs (dinv-scaled bf16). Blocks >= NB pack W1/W2.
// pk entry = (src<<8)|(dst&255); csr entry = src<<8 (byte offset of xs row).
__global__ __launch_bounds__(256) void kb_fused(const int* __restrict__ pk,
    const int* __restrict__ bOff,
    int* __restrict__ rp, int* __restrict__ csr, float* __restrict__ dinv,
    const float2* __restrict__ x2, unsigned int* __restrict__ xb,
    const float* __restrict__ W1, unsigned short* __restrict__ W1p,
    const float* __restrict__ W2, unsigned short* __restrict__ W2p,
    int n, int NB, int E){
  int t = threadIdx.x;
  int b = blockIdx.x;
  if (b >= NB){
    int idx = (b-NB)*256 + t;
    if (idx < 4096) packW(W1, W1p, idx, 256, 16);        // K=128,N=256
    else            packW(W2, W2p, idx-4096, 128, 8);    // K=256,N=128
    return;
  }
  __shared__ int c[256];
  __shared__ int sh[256];
  __shared__ int cur[256];
  __shared__ float dv[256];
  int s = bOff[b], e2 = bOff[b+1];
  c[t]=0; __syncthreads();
  for (int i=s+t;i<e2;i+=256) atomicAdd(&c[pk[i]&255], 1);
  __syncthreads();
  int deg = c[t];
  sh[t]=deg; __syncthreads();
  for (int o=1;o<256;o<<=1){
    int x = (t>=o) ? sh[t-o] : 0;
    __syncthreads();
    sh[t]+=x;
    __syncthreads();
  }
  int excl = sh[t]-deg;
  int node = b*256+t;
  float dnv = rsqrtf((float)(deg+1));
  if (node<n){
    rp[node] = s + excl;
    dinv[node] = dnv;
  }
  if (b==NB-1 && t==0) rp[n] = E;
  cur[t] = s + excl;
  dv[t] = dnv;
  __syncthreads();
  for (int i=s+t;i<e2;i+=256){
    int p = pk[i];
    int r = atomicAdd(&cur[p&255], 1);
    csr[r] = p & (int)0xFFFFFF00u;
  }
  // cvt: xs[row] = bf16(dinv[row] * x[row]) for this bucket's rows
  int base_node = b*256;
  int rows = n - base_node; if (rows > 256) rows = 256;
  int j = t & 63;
  for (int rb = t>>6; rb < rows; rb += 4){
    int nd = base_node + rb;
    float d = dv[rb];
    float2 v = x2[(size_t)nd*64 + j];
    xb[(size_t)nd*64 + j] = packbf2(d*v.x, d*v.y);
  }
}

#define ACC8(V) { a0+=bflo(V.x); a1+=bfhi(V.x); a2+=bflo(V.y); a3+=bfhi(V.y); \
                  a4+=bflo(V.z); a5+=bfhi(V.z); a6+=bflo(V.w); a7+=bfhi(V.w); }

// LDS granule swizzle: row-major 64x256B tile, 16B granules, g' = (g&8)|((g&7)^(row&7))
DEVI int lds_g(int row, int g){ return row*256 + (((g & 8) | ((g & 7) ^ (row & 7)))<<4); }

// Fused agg1 + GEMM1: phase A aggregates 64 rows into LDS (bf16, swizzled),
// phase B computes H1 = relu((LDS tile) @ W1p + b1) via MFMA.
__global__ __launch_bounds__(256) void k_aggemm1(
    const unsigned int* __restrict__ xs, const int* __restrict__ rp,
    const int* __restrict__ csr, const float* __restrict__ dinv,
    const unsigned short* __restrict__ Wp, const float* __restrict__ bias,
    unsigned short* __restrict__ C, int n){
  __shared__ unsigned char At[64*256];
  int l = threadIdx.x & 63;
  int w = threadIdx.x >> 6;
  int r0 = blockIdx.x*64;
  int q = l & 15;
  int h = l >> 4;
  const char* xbase = (const char*)xs;
  // ---- phase A: aggregate 16 nodes per wave ----
  for (int nn=0; nn<16; ++nn){
    int row = w*16 + nn;
    int node = r0 + row;
    float a0=0,a1=0,a2=0,a3=0,a4=0,a5=0,a6=0,a7=0;
    float dn = 0.f;
    if (node < n){
      int e = rp[node], end = rp[node+1];
      int p = e;
      int nf = (end - e) >> 4;
      for (int blk=0; blk<nf; ++blk, p+=16){
        uint4 v[4];
        #pragma unroll
        for (int i=0;i<4;i++){
          int boff = csr[p + 4*i + h];
          v[i] = *(const uint4*)(xbase + (size_t)(unsigned)boff + q*16);
        }
        ACC8(v[0]); ACC8(v[1]); ACC8(v[2]); ACC8(v[3]);
      }
      int rem = end - p;
      if (rem >= 8){
        uint4 v[2];
        #pragma unroll
        for (int i=0;i<2;i++){
          int boff = csr[p + 4*i + h];
          v[i] = *(const uint4*)(xbase + (size_t)(unsigned)boff + q*16);
        }
        ACC8(v[0]); ACC8(v[1]);
        p += 8; rem -= 8;
      }
      if (rem > 0){
        uint4 v[2];
        #pragma unroll
        for (int i=0;i<2;i++){
          int ei = p + 4*i + h;
          int ec = ei < end-1 ? ei : end-1;
          int boff = csr[ec];
          uint4 tv = *(const uint4*)(xbase + (size_t)(unsigned)boff + q*16);
          if (ei >= end){ tv.x=0; tv.y=0; tv.z=0; tv.w=0; }
          v[i] = tv;
        }
        ACC8(v[0]); ACC8(v[1]);
      }
      a0 += __shfl_xor(a0,16); a0 += __shfl_xor(a0,32);
      a1 += __shfl_xor(a1,16); a1 += __shfl_xor(a1,32);
      a2 += __shfl_xor(a2,16); a2 += __shfl_xor(a2,32);
      a3 += __shfl_xor(a3,16); a3 += __shfl_xor(a3,32);
      a4 += __shfl_xor(a4,16); a4 += __shfl_xor(a4,32);
      a5 += __shfl_xor(a5,16); a5 += __shfl_xor(a5,32);
      a6 += __shfl_xor(a6,16); a6 += __shfl_xor(a6,32);
      a7 += __shfl_xor(a7,16); a7 += __shfl_xor(a7,32);
      uint4 sv = *(const uint4*)(xbase + (size_t)node*256 + q*16);
      ACC8(sv);
      dn = dinv[node];
    }
    if (h == 0){
      uint4 o;
      o.x = packbf2(a0*dn, a1*dn);
      o.y = packbf2(a2*dn, a3*dn);
      o.z = packbf2(a4*dn, a5*dn);
      o.w = packbf2(a6*dn, a7*dn);
      *(uint4*)(At + lds_g(row, q)) = o;
    }
  }
  __syncthreads();
  // ---- phase B: GEMM 64x256 = At @ W1p, bias+relu ----
  int lr = l & 15, lg = l >> 4;
  int c0 = w*64;
  f32x4 acc[4][4];
  #pragma unroll
  for (int i=0;i<4;i++)
    #pragma unroll
    for (int j2=0;j2<4;j2++)
      acc[i][j2] = f32x4{0.f,0.f,0.f,0.f};
  #pragma unroll
  for (int ks=0; ks<4; ++ks){
    bf16x8 a[4], b[4];
    #pragma unroll
    for (int ar=0;ar<4;ar++){
      int row = ar*16 + lr;
      int ga = ks*4 + lg;
      union { uint4 u; bf16x8 v; } t2;
      t2.u = *(const uint4*)(At + lds_g(row, ga));
      a[ar] = t2.v;
    }
    #pragma unroll
    for (int cb=0;cb<4;cb++){
      int cf = (c0>>4) + cb;
      const uint4* p = (const uint4*)(Wp + ((size_t)(ks*16 + cf)*64 + l)*8);
      union { uint4 u; bf16x8 v; } t2; t2.u = *p; b[cb] = t2.v;
    }
    #pragma unroll
    for (int ar=0;ar<4;ar++)
      #pragma unroll
      for (int cb=0;cb<4;cb++)
        acc[ar][cb] = __builtin_amdgcn_mfma_f32_16x16x32_bf16(a[ar], b[cb], acc[ar][cb], 0, 0, 0);
  }
  #pragma unroll
  for (int ar=0;ar<4;ar++){
    #pragma unroll
    for (int i=0;i<4;i++){
      int grow = r0 + ar*16 + lg*4 + i;
      if (grow < n){
        #pragma unroll
        for (int cb=0;cb<4;cb++){
          int col = c0 + cb*16 + lr;
          float v = acc[ar][cb][i] + bias[col];
          v = fmaxf(v, 0.f);
          C[(size_t)grow*256 + col] = f2bf(v);
        }
      }
    }
  }
}

// Aggregate pre-scaled rows (standalone, layer 2 final):
// out[d] = dinv[d] * (sum xs[s] + xs[d]) + bias, f32 output.
__global__ __launch_bounds__(256) void k_agg2(
    const unsigned int* __restrict__ xs, const int* __restrict__ rp,
    const int* __restrict__ csr, const float* __restrict__ dinv,
    const float* __restrict__ bias, float* __restrict__ outf, int n){
  int node = blockIdx.x*4 + (threadIdx.x>>6);
  if (node >= n) return;
  int l = threadIdx.x & 63;
  int q = l & 15;
  int h = l >> 4;
  const char* xbase = (const char*)xs;
  float a0=0,a1=0,a2=0,a3=0,a4=0,a5=0,a6=0,a7=0;
  int e = rp[node], end = rp[node+1];
  int p = e;
  int nf = (end - e) >> 4;
  for (int blk=0; blk<nf; ++blk, p+=16){
    uint4 v[4];
    #pragma unroll
    for (int i=0;i<4;i++){
      int boff = csr[p + 4*i + h];
      v[i] = *(const uint4*)(xbase + (size_t)(unsigned)boff + q*16);
    }
    ACC8(v[0]); ACC8(v[1]); ACC8(v[2]); ACC8(v[3]);
  }
  int rem = end - p;
  if (rem >= 8){
    uint4 v[2];
    #pragma unroll
    for (int i=0;i<2;i++){
      int boff = csr[p + 4*i + h];
      v[i] = *(const uint4*)(xbase + (size_t)(unsigned)boff + q*16);
    }
    ACC8(v[0]); ACC8(v[1]);
    p += 8; rem -= 8;
  }
  if (rem > 0){
    uint4 v[2];
    #pragma unroll
    for (int i=0;i<2;i++){
      int ei = p + 4*i + h;
      int ec = ei < end-1 ? ei : end-1;
      int boff = csr[ec];
      uint4 t = *(const uint4*)(xbase + (size_t)(unsigned)boff + q*16);
      if (ei >= end){ t.x=0; t.y=0; t.z=0; t.w=0; }
      v[i] = t;
    }
    ACC8(v[0]); ACC8(v[1]);
  }
  a0 += __shfl_xor(a0,16); a0 += __shfl_xor(a0,32);
  a1 += __shfl_xor(a1,16); a1 += __shfl_xor(a1,32);
  a2 += __shfl_xor(a2,16); a2 += __shfl_xor(a2,32);
  a3 += __shfl_xor(a3,16); a3 += __shfl_xor(a3,32);
  a4 += __shfl_xor(a4,16); a4 += __shfl_xor(a4,32);
  a5 += __shfl_xor(a5,16); a5 += __shfl_xor(a5,32);
  a6 += __shfl_xor(a6,16); a6 += __shfl_xor(a6,32);
  a7 += __shfl_xor(a7,16); a7 += __shfl_xor(a7,32);
  uint4 sv = *(const uint4*)(xbase + (size_t)node*256 + q*16);
  ACC8(sv);
  float dn = dinv[node];
  if (h < 2){
    const float4 bb = *(const float4*)(bias + 8*q + 4*h);
    f32x4 r;
    r.x = (h ? a4 : a0)*dn + bb.x;
    r.y = (h ? a5 : a1)*dn + bb.y;
    r.z = (h ? a6 : a2)*dn + bb.z;
    r.w = (h ? a7 : a3)*dn + bb.w;
    __builtin_nontemporal_store(r, (f32x4*)(outf + (size_t)node*128 + 8*q + 4*h));
  }
}

// GEMM2: T = dinv .* (H1 @ W2p)  (bf16 out, rowscale epilogue)
__global__ __launch_bounds__(256) void k_gemm2(
    const unsigned short* __restrict__ A, const unsigned short* __restrict__ Wp,
    const float* __restrict__ rowscale, unsigned short* __restrict__ C, int M){
  constexpr int K = 256, N = 128;
  constexpr int KS = K/32;        // 8
  constexpr int NF = N/16;        // 8
  constexpr int NWC = N/64;       // 2
  constexpr int NWR = 4/NWC;      // 2
  constexpr int BM = 64*NWR;      // 128
  int l = threadIdx.x & 63;
  int w = threadIdx.x >> 6;
  int wr = w / NWC, wc = w % NWC;
  int r0 = blockIdx.x*BM + wr*64;
  int c0 = wc*64;
  int lr = l & 15, lg = l >> 4;
  f32x4 acc[4][4];
  #pragma unroll
  for (int i=0;i<4;i++)
    #pragma unroll
    for (int j=0;j<4;j++)
      acc[i][j] = f32x4{0.f,0.f,0.f,0.f};
  for (int ks=0; ks<KS; ++ks){
    bf16x8 a[4], b[4];
    #pragma unroll
    for (int ar=0;ar<4;ar++){
      int row = r0 + ar*16 + lr;
      if (row > M-1) row = M-1;
      const uint4* p = (const uint4*)(A + (size_t)row*K + ks*32 + lg*8);
      union { uint4 u; bf16x8 v; } t; t.u = *p; a[ar] = t.v;
    }
    #pragma unroll
    for (int cb=0;cb<4;cb++){
      int cf = (c0>>4) + cb;
      const uint4* p = (const uint4*)(Wp + ((size_t)(ks*NF + cf)*64 + l)*8);
      union { uint4 u; bf16x8 v; } t; t.u = *p; b[cb] = t.v;
    }
    #pragma unroll
    for (int ar=0;ar<4;ar++)
      #pragma unroll
      for (int cb=0;cb<4;cb++)
        acc[ar][cb] = __builtin_amdgcn_mfma_f32_16x16x32_bf16(a[ar], b[cb], acc[ar][cb], 0, 0, 0);
  }
  #pragma unroll
  for (int ar=0;ar<4;ar++){
    #pragma unroll
    for (int i=0;i<4;i++){
      int row = r0 + ar*16 + lg*4 + i;
      if (row < M){
        float rs = rowscale[row];
        #pragma unroll
        for (int cb=0;cb<4;cb++){
          int col = c0 + cb*16 + lr;
          C[(size_t)row*N + col] = f2bf(acc[ar][cb][i] * rs);
        }
      }
    }
  }
}

extern "C" void kernel_launch(void* const* d_in, const int* in_sizes, int n_in,
                              void* d_out, int out_size, void* d_ws, size_t ws_size,
                              hipStream_t stream){
  const float* x  = (const float*)d_in[0];
  const int*   ei = (const int*)d_in[1];
  const float* W1 = (const float*)d_in[2];
  const float* b1 = (const float*)d_in[3];
  const float* W2 = (const float*)d_in[4];
  const float* b2 = (const float*)d_in[5];
  const int IN_F = 128, H_F = 256, OUT_F = 128;
  int n = in_sizes[0] / IN_F;      // 100000
  int E = in_sizes[1] / 2;         // 1600000
  const int* srcI = ei;
  const int* dstI = ei + E;
  const int NB  = (n+255)>>8;      // fine buckets (256 nodes)
  const int NBC = (n+2047)>>11;    // coarse buckets (2048 nodes)

  char* ws = (char*)d_ws;
  size_t off = 0;
  auto alloc = [&](size_t bytes)->char*{
    char* p = ws + off; off += (bytes + 255) & ~(size_t)255; return p;
  };
  int*   rp    = (int*)  alloc(((size_t)n+1)*4);
  float* dinv  = (float*)alloc((size_t)n*4);
  int*   bCnt  = (int*)  alloc((size_t)NB*4);
  int*   bOff  = (int*)  alloc(((size_t)NB+1)*4);
  int*   bCur  = (int*)  alloc((size_t)NB*4);
  int*   cCur  = (int*)  alloc(((size_t)NBC+1)*4);
  unsigned short* W1p = (unsigned short*)alloc((size_t)IN_F*H_F*2);
  unsigned short* W2p = (unsigned short*)alloc((size_t)H_F*OUT_F*2);
  int*   csr   = (int*)  alloc((size_t)E*4);
  unsigned int* xb = (unsigned int*)alloc((size_t)n*(IN_F/2)*4);  // reused as T after GEMM1
  unsigned short* H1 = (unsigned short*)alloc((size_t)n*H_F*2);
  // pass-1 edge pairs + packed pass-2 output alias H1 (dead until aggemm1)
  int* srcc = (int*)H1;
  int* dstc = srcc + E;
  int* pk   = dstc + E;

  int NCH = (E + CHUNK - 1)/CHUNK;
  int NSC = (E + SCH - 1)/SCH;

  k_zero<<<(NB+255)/256,256,0,stream>>>(bCnt, NB);
  kb_hist<<<NCH,256,0,stream>>>(dstI, bCnt, E, NB);
  kb_scan<<<1,256,0,stream>>>(bCnt, bOff, bCur, cCur, NB, NBC);
  kb_scat1<<<NSC,512,0,stream>>>(srcI, dstI, cCur, srcc, dstc, E, NBC);
  kb_scat2<<<NSC,512,0,stream>>>(srcc, dstc, bCur, pk, E, NB);
  kb_fused<<<NB+32,256,0,stream>>>(pk, bOff, rp, csr, dinv,
                                   (const float2*)x, xb, W1, W1p, W2, W2p, n, NB, E);
  // layer 1 fused: H1 = relu((A_hat @ xs) @ W1 + b1)
  k_aggemm1<<<(n+63)/64,256,0,stream>>>(xb, rp, csr, dinv, W1p, b1, H1, n);
  // layer 2: T = dinv .* (H1 @ W2) ; out = dinv .* gather(T) + b2
  unsigned int* T = xb;
  k_gemm2<<<(n+127)/128,256,0,stream>>>(H1, W2p, dinv, (unsigned short*)T, n);
  k_agg2<<<(n+3)/4,256,0,stream>>>(T, rp, csr, dinv, b2, (float*)d_out, n);
}

// Round 10
// 261.202 us; speedup vs baseline: 1.2428x; 1.2428x over previous
//
#include <hip/hip_runtime.h>

typedef __bf16 bf16x8 __attribute__((ext_vector_type(8)));
typedef float f32x4 __attribute__((ext_vector_type(4)));

#define DEVI static __device__ __forceinline__
#define CHUNK 4096
#define SCH 8192

DEVI unsigned short f2bf(float f){
  unsigned int x = __builtin_bit_cast(unsigned int, f);
  x = (x + 0x7fffu + ((x >> 16) & 1u)) >> 16;
  return (unsigned short)x;
}
DEVI unsigned int packbf2(float a, float b){
  return (unsigned int)f2bf(a) | ((unsigned int)f2bf(b) << 16);
}
DEVI float bflo(unsigned int u){ return __builtin_bit_cast(float, u << 16); }
DEVI float bfhi(unsigned int u){ return __builtin_bit_cast(float, u & 0xffff0000u); }

__global__ void k_zero(int* __restrict__ p, int n){
  int i = blockIdx.x*256 + threadIdx.x;
  if (i < n) p[i] = 0;
}

// ---- two-level bucketed CSR build ----
// fine bucket = 256 consecutive dst nodes (391); coarse = 2048 nodes (49).

__global__ __launch_bounds__(256) void kb_hist(const int* __restrict__ dst,
    int* __restrict__ bucketCnt, int E, int NB){
  __shared__ int h[2048];
  for (int i=threadIdx.x;i<NB;i+=256) h[i]=0;
  __syncthreads();
  int base = blockIdx.x*CHUNK;
  int lim = base+CHUNK < E ? base+CHUNK : E;
  for (int i = base+threadIdx.x; i < lim; i += 256)
    atomicAdd(&h[dst[i]>>8], 1);
  __syncthreads();
  for (int i=threadIdx.x;i<NB;i+=256)
    if (h[i]) atomicAdd(&bucketCnt[i], h[i]);
}

// one block: fine scan (bOff/bCur) + coarse cursors (cCur[c]=bOff[c*8])
__global__ __launch_bounds__(256) void kb_scan(const int* __restrict__ bucketCnt,
    int* __restrict__ bucketOff, int* __restrict__ bucketCur,
    int* __restrict__ cCur, int NB, int NBC){
  __shared__ int sh[256];
  int t = threadIdx.x;
  int per = (NB+255)/256;
  int vals[8];
  int lsum = 0;
  for (int j=0;j<per;j++){
    int i = t*per+j;
    int v = (i<NB) ? bucketCnt[i] : 0;
    vals[j]=v; lsum+=v;
  }
  sh[t]=lsum; __syncthreads();
  for (int off=1; off<256; off<<=1){
    int x = (t>=off) ? sh[t-off] : 0;
    __syncthreads();
    sh[t] += x;
    __syncthreads();
  }
  int run = sh[t]-lsum;
  for (int j=0;j<per;j++){
    int i = t*per+j;
    if (i<NB){ bucketOff[i]=run; bucketCur[i]=run; }
    run += vals[j];
  }
  if (t==255) bucketOff[NB]=run;
  __syncthreads();
  for (int c=t;c<NBC;c+=256){
    int f = c*8;
    cCur[c] = bucketOff[f < NB ? f : NB];
  }
}

// pass 1: chunked LDS-histogram scatter by coarse bucket (dst>>11).
// writes PACKED word (src<<11) | (dst & 2047).
__global__ __launch_bounds__(512) void kb_scat1(const int* __restrict__ src,
    const int* __restrict__ dst, int* __restrict__ cur,
    int* __restrict__ p1, int E, int NBK){
  __shared__ int h[64];
  __shared__ int baseSh[64];
  int t = threadIdx.x;
  if (t < NBK){ h[t]=0; }
  __syncthreads();
  int base = blockIdx.x*SCH;
  int lim = base+SCH < E ? base+SCH : E;
  for (int i = base+t; i < lim; i += 512)
    atomicAdd(&h[dst[i]>>11], 1);
  __syncthreads();
  if (t < NBK){
    int c = h[t];
    baseSh[t] = c ? atomicAdd(&cur[t], c) : 0;
    h[t] = 0;
  }
  __syncthreads();
  for (int i = base+t; i < lim; i += 512){
    int d = dst[i];
    int b = d>>11;
    int r = atomicAdd(&h[b], 1);
    int p = baseSh[b] + r;
    p1[p] = (src[i]<<11) | (d & 2047);
  }
}

// pass 2: per-coarse-bucket blocks (grid = NBC*8). Coarse id from blockIdx;
// bins the packed p1 entries into fine buckets; writes (src<<8)|(dst&255).
__global__ __launch_bounds__(512) void kb_scat2(const int* __restrict__ p1,
    const int* __restrict__ bOff, int* __restrict__ cur,
    int* __restrict__ pk, int NB){
  __shared__ int h[8];
  __shared__ int baseSh[8];
  int t = threadIdx.x;
  int bc = blockIdx.x >> 3;
  int sub = blockIdx.x & 7;
  int s = bOff[bc*8];
  int fe = bc*8+8; if (fe > NB) fe = NB;
  int e = bOff[fe];
  if (t < 8) h[t] = 0;
  __syncthreads();
  for (int i = s + sub*512 + t; i < e; i += 4096)
    atomicAdd(&h[(p1[i]>>8)&7], 1);
  __syncthreads();
  if (t < 8){
    int c2 = h[t];
    baseSh[t] = c2 ? atomicAdd(&cur[bc*8+t], c2) : 0;
    h[t] = 0;
  }
  __syncthreads();
  for (int i = s + sub*512 + t; i < e; i += 4096){
    int p = p1[i];
    int f = (p>>8)&7;
    int r = atomicAdd(&h[f], 1);
    int pos = baseSh[f] + r;
    pk[pos] = ((p>>11)<<8) | (p&255);
  }
}

// Pack row-major fp32 W[K][N] into MFMA B-fragment order:
// frag (ks, cf), lane l, elem j  <-  W[ks*32 + (l>>4)*8 + j][cf*16 + (l&15)]
DEVI void packW(const float* __restrict__ W, unsigned short* __restrict__ Wp,
                int idx, int N, int NF){
  int l = idx & 63;
  int frag = idx >> 6;
  int cf = frag % NF;
  int ks = frag / NF;
  int kbase = ks*32 + (l>>4)*8;
  int col = cf*16 + (l&15);
  unsigned short* dp = Wp + (size_t)idx*8;
  #pragma unroll
  for (int j=0;j<8;j++) dp[j] = f2bf(W[(size_t)(kbase+j)*N + col]);
}

// Fused per-bucket: count -> LDS scan -> rp/dinv -> rank & write csr -> cvt
// this bucket's x rows into xs (dinv-scaled bf16). Blocks >= NB pack W1/W2.
// pk entry = (src<<8)|(dst&255); csr entry = src<<8 (byte offset of xs row).
__global__ __launch_bounds__(256) void kb_fused(const int* __restrict__ pk,
    const int* __restrict__ bOff,
    int* __restrict__ rp, int* __restrict__ csr, float* __restrict__ dinv,
    const float2* __restrict__ x2, unsigned int* __restrict__ xb,
    const float* __restrict__ W1, unsigned short* __restrict__ W1p,
    const float* __restrict__ W2, unsigned short* __restrict__ W2p,
    int n, int NB, int E){
  int t = threadIdx.x;
  int b = blockIdx.x;
  if (b >= NB){
    int idx = (b-NB)*256 + t;
    if (idx < 4096) packW(W1, W1p, idx, 256, 16);        // K=128,N=256
    else            packW(W2, W2p, idx-4096, 128, 8);    // K=256,N=128
    return;
  }
  __shared__ int c[256];
  __shared__ int sh[256];
  __shared__ int cur[256];
  __shared__ float dv[256];
  int s = bOff[b], e2 = bOff[b+1];
  c[t]=0; __syncthreads();
  for (int i=s+t;i<e2;i+=256) atomicAdd(&c[pk[i]&255], 1);
  __syncthreads();
  int deg = c[t];
  sh[t]=deg; __syncthreads();
  for (int o=1;o<256;o<<=1){
    int x = (t>=o) ? sh[t-o] : 0;
    __syncthreads();
    sh[t]+=x;
    __syncthreads();
  }
  int excl = sh[t]-deg;
  int node = b*256+t;
  float dnv = rsqrtf((float)(deg+1));
  if (node<n){
    rp[node] = s + excl;
    dinv[node] = dnv;
  }
  if (b==NB-1 && t==0) rp[n] = E;
  cur[t] = s + excl;
  dv[t] = dnv;
  __syncthreads();
  for (int i=s+t;i<e2;i+=256){
    int p = pk[i];
    int r = atomicAdd(&cur[p&255], 1);
    csr[r] = p & (int)0xFFFFFF00u;
  }
  // cvt: xs[row] = bf16(dinv[row] * x[row]) for this bucket's rows
  int base_node = b*256;
  int rows = n - base_node; if (rows > 256) rows = 256;
  int j = t & 63;
  for (int rb = t>>6; rb < rows; rb += 4){
    int nd = base_node + rb;
    float d = dv[rb];
    float2 v = x2[(size_t)nd*64 + j];
    xb[(size_t)nd*64 + j] = packbf2(d*v.x, d*v.y);
  }
}

// Aggregate pre-scaled rows: out[d] = dinv[d] * (sum_{s in N(d)} xs[s] + xs[d])
// One wave per node. Lane l: quarter h=l>>4 handles edge sub-slot h, q=l&15
// owns features [8q, 8q+8) (16B uint4). Each gather instr covers 4 edges x 16B.
// Quarter partials reduced via shfl_xor(16/32). csr holds byte offsets.
#define ACC8(V) { a0+=bflo(V.x); a1+=bfhi(V.x); a2+=bflo(V.y); a3+=bfhi(V.y); \
                  a4+=bflo(V.z); a5+=bfhi(V.z); a6+=bflo(V.w); a7+=bfhi(V.w); }

template<bool FINAL>
__global__ __launch_bounds__(256) void k_agg(
    const unsigned int* __restrict__ xs, const int* __restrict__ rp,
    const int* __restrict__ csr, const float* __restrict__ dinv,
    const float* __restrict__ bias, unsigned int* __restrict__ outb,
    float* __restrict__ outf, int n){
  int node = blockIdx.x*4 + (threadIdx.x>>6);
  if (node >= n) return;
  int l = threadIdx.x & 63;
  int q = l & 15;
  int h = l >> 4;
  const char* xbase = (const char*)xs;
  float a0=0,a1=0,a2=0,a3=0,a4=0,a5=0,a6=0,a7=0;
  int e = rp[node], end = rp[node+1];
  int p = e;
  int nf = (end - e) >> 4;
  for (int blk=0; blk<nf; ++blk, p+=16){
    uint4 v[4];
    #pragma unroll
    for (int i=0;i<4;i++){
      int boff = csr[p + 4*i + h];
      v[i] = *(const uint4*)(xbase + (size_t)(unsigned)boff + q*16);
    }
    ACC8(v[0]); ACC8(v[1]); ACC8(v[2]); ACC8(v[3]);
  }
  int rem = end - p;
  if (rem >= 8){
    uint4 v[2];
    #pragma unroll
    for (int i=0;i<2;i++){
      int boff = csr[p + 4*i + h];
      v[i] = *(const uint4*)(xbase + (size_t)(unsigned)boff + q*16);
    }
    ACC8(v[0]); ACC8(v[1]);
    p += 8; rem -= 8;
  }
  if (rem > 0){
    uint4 v[2];
    #pragma unroll
    for (int i=0;i<2;i++){
      int ei = p + 4*i + h;
      int ec = ei < end-1 ? ei : end-1;
      int boff = csr[ec];
      uint4 t = *(const uint4*)(xbase + (size_t)(unsigned)boff + q*16);
      if (ei >= end){ t.x=0; t.y=0; t.z=0; t.w=0; }
      v[i] = t;
    }
    ACC8(v[0]); ACC8(v[1]);
  }
  a0 += __shfl_xor(a0,16); a0 += __shfl_xor(a0,32);
  a1 += __shfl_xor(a1,16); a1 += __shfl_xor(a1,32);
  a2 += __shfl_xor(a2,16); a2 += __shfl_xor(a2,32);
  a3 += __shfl_xor(a3,16); a3 += __shfl_xor(a3,32);
  a4 += __shfl_xor(a4,16); a4 += __shfl_xor(a4,32);
  a5 += __shfl_xor(a5,16); a5 += __shfl_xor(a5,32);
  a6 += __shfl_xor(a6,16); a6 += __shfl_xor(a6,32);
  a7 += __shfl_xor(a7,16); a7 += __shfl_xor(a7,32);
  // self term
  uint4 sv = *(const uint4*)(xbase + (size_t)node*256 + q*16);
  ACC8(sv);
  float dn = dinv[node];
  if constexpr (FINAL){
    if (h < 2){
      const float4 bb = *(const float4*)(bias + 8*q + 4*h);
      f32x4 r;
      r.x = (h ? a4 : a0)*dn + bb.x;
      r.y = (h ? a5 : a1)*dn + bb.y;
      r.z = (h ? a6 : a2)*dn + bb.z;
      r.w = (h ? a7 : a3)*dn + bb.w;
      __builtin_nontemporal_store(r, (f32x4*)(outf + (size_t)node*128 + 8*q + 4*h));
    }
  } else {
    if (h == 0){
      uint4 o;
      o.x = packbf2(a0*dn, a1*dn);
      o.y = packbf2(a2*dn, a3*dn);
      o.z = packbf2(a4*dn, a5*dn);
      o.w = packbf2(a6*dn, a7*dn);
      *(uint4*)((char*)outb + (size_t)node*256 + q*16) = o;
    }
  }
}

// C[M][N] (bf16) = A[M][K] (bf16, row-major) @ Wp (packed frags)
// [+bias+relu] or [*rowscale] epilogue.
// 4 waves/block; wave computes 64x64 via 4x4 grid of 16x16x32 MFMA fragments.
template<int K, int N, bool BIASRELU, bool ROWSCALE>
__global__ __launch_bounds__(256) void k_gemm(
    const unsigned short* __restrict__ A, const unsigned short* __restrict__ Wp,
    const float* __restrict__ bias, const float* __restrict__ rowscale,
    unsigned short* __restrict__ C, int M){
  constexpr int KS = K/32;
  constexpr int NF = N/16;
  constexpr int NWC = N/64;       // waves along cols
  constexpr int NWR = 4/NWC;      // waves along rows
  constexpr int BM = 64*NWR;
  int l = threadIdx.x & 63;
  int w = threadIdx.x >> 6;
  int wr = w / NWC, wc = w % NWC;
  int r0 = blockIdx.x*BM + wr*64;
  int c0 = wc*64;
  int lr = l & 15, lg = l >> 4;
  f32x4 acc[4][4];
  #pragma unroll
  for (int i=0;i<4;i++)
    #pragma unroll
    for (int j=0;j<4;j++)
      acc[i][j] = f32x4{0.f,0.f,0.f,0.f};
  for (int ks=0; ks<KS; ++ks){
    bf16x8 a[4], b[4];
    #pragma unroll
    for (int ar=0;ar<4;ar++){
      int row = r0 + ar*16 + lr;
      if (row > M-1) row = M-1;
      const uint4* p = (const uint4*)(A + (size_t)row*K + ks*32 + lg*8);
      union { uint4 u; bf16x8 v; } t; t.u = *p; a[ar] = t.v;
    }
    #pragma unroll
    for (int cb=0;cb<4;cb++){
      int cf = (c0>>4) + cb;
      const uint4* p = (const uint4*)(Wp + ((size_t)(ks*NF + cf)*64 + l)*8);
      union { uint4 u; bf16x8 v; } t; t.u = *p; b[cb] = t.v;
    }
    #pragma unroll
    for (int ar=0;ar<4;ar++)
      #pragma unroll
      for (int cb=0;cb<4;cb++)
        acc[ar][cb] = __builtin_amdgcn_mfma_f32_16x16x32_bf16(a[ar], b[cb], acc[ar][cb], 0, 0, 0);
  }
  #pragma unroll
  for (int ar=0;ar<4;ar++){
    #pragma unroll
    for (int i=0;i<4;i++){
      int row = r0 + ar*16 + lg*4 + i;
      if (row < M){
        float rs = 1.f;
        if constexpr (ROWSCALE) rs = rowscale[row];
        #pragma unroll
        for (int cb=0;cb<4;cb++){
          int col = c0 + cb*16 + lr;
          float v = acc[ar][cb][i];
          if constexpr (BIASRELU){ v += bias[col]; v = fmaxf(v, 0.f); }
          if constexpr (ROWSCALE) v *= rs;
          C[(size_t)row*N + col] = f2bf(v);
        }
      }
    }
  }
}

extern "C" void kernel_launch(void* const* d_in, const int* in_sizes, int n_in,
                              void* d_out, int out_size, void* d_ws, size_t ws_size,
                              hipStream_t stream){
  const float* x  = (const float*)d_in[0];
  const int*   ei = (const int*)d_in[1];
  const float* W1 = (const float*)d_in[2];
  const float* b1 = (const float*)d_in[3];
  const float* W2 = (const float*)d_in[4];
  const float* b2 = (const float*)d_in[5];
  const int IN_F = 128, H_F = 256, OUT_F = 128;
  int n = in_sizes[0] / IN_F;      // 100000
  int E = in_sizes[1] / 2;         // 1600000
  const int* srcI = ei;
  const int* dstI = ei + E;
  const int NB  = (n+255)>>8;      // fine buckets (256 nodes)
  const int NBC = (n+2047)>>11;    // coarse buckets (2048 nodes)

  char* ws = (char*)d_ws;
  size_t off = 0;
  auto alloc = [&](size_t bytes)->char*{
    char* p = ws + off; off += (bytes + 255) & ~(size_t)255; return p;
  };
  int*   rp    = (int*)  alloc(((size_t)n+1)*4);
  float* dinv  = (float*)alloc((size_t)n*4);
  int*   bCnt  = (int*)  alloc((size_t)NB*4);
  int*   bOff  = (int*)  alloc(((size_t)NB+1)*4);
  int*   bCur  = (int*)  alloc((size_t)NB*4);
  int*   cCur  = (int*)  alloc(((size_t)NBC+1)*4);
  unsigned short* W1p = (unsigned short*)alloc((size_t)IN_F*H_F*2);
  unsigned short* W2p = (unsigned short*)alloc((size_t)H_F*OUT_F*2);
  int*   csr   = (int*)  alloc((size_t)E*4);
  unsigned int* xb = (unsigned int*)alloc((size_t)n*(IN_F/2)*4);  // reused as T after GEMM1
  unsigned int* AX = (unsigned int*)alloc((size_t)n*(IN_F/2)*4);
  unsigned short* H1 = (unsigned short*)alloc((size_t)n*H_F*2);
  // packed pass-1 and pass-2 edge words alias H1 (dead until GEMM1 writes H1)
  int* p1 = (int*)H1;
  int* pk = p1 + E;

  int NCH = (E + CHUNK - 1)/CHUNK;
  int NSC = (E + SCH - 1)/SCH;

  k_zero<<<(NB+255)/256,256,0,stream>>>(bCnt, NB);
  kb_hist<<<NCH,256,0,stream>>>(dstI, bCnt, E, NB);
  kb_scan<<<1,256,0,stream>>>(bCnt, bOff, bCur, cCur, NB, NBC);
  kb_scat1<<<NSC,512,0,stream>>>(srcI, dstI, cCur, p1, E, NBC);
  kb_scat2<<<NBC*8,512,0,stream>>>(p1, bOff, bCur, pk, NB);
  kb_fused<<<NB+32,256,0,stream>>>(pk, bOff, rp, csr, dinv,
                                   (const float2*)x, xb, W1, W1p, W2, W2p, n, NB, E);
  // layer 1: AX = A_hat @ xs ; H1 = relu(AX @ W1 + b1)
  k_agg<false><<<(n+3)/4,256,0,stream>>>(xb, rp, csr, dinv, nullptr, AX, nullptr, n);
  k_gemm<128,256,true,false><<<(n+63)/64,256,0,stream>>>((const unsigned short*)AX, W1p, b1, nullptr, H1, n);
  // layer 2: T = dinv .* (H1 @ W2) ; out = dinv .* gather(T) + b2
  unsigned int* T = xb;
  k_gemm<256,128,false,true><<<(n+127)/128,256,0,stream>>>(H1, W2p, nullptr, dinv, (unsigned short*)T, n);
  k_agg<true><<<(n+3)/4,256,0,stream>>>(T, rp, csr, dinv, b2, nullptr, (float*)d_out, n);
}

// Round 11
// 231.683 us; speedup vs baseline: 1.4011x; 1.1274x over previous
//
#include <hip/hip_runtime.h>

typedef __bf16 bf16x8 __attribute__((ext_vector_type(8)));
typedef float f32x4 __attribute__((ext_vector_type(4)));

#define DEVI static __device__ __forceinline__
#define SCH 8192
#define CAP 49152

DEVI unsigned short f2bf(float f){
  unsigned int x = __builtin_bit_cast(unsigned int, f);
  x = (x + 0x7fffu + ((x >> 16) & 1u)) >> 16;
  return (unsigned short)x;
}
DEVI unsigned int packbf2(float a, float b){
  return (unsigned int)f2bf(a) | ((unsigned int)f2bf(b) << 16);
}
DEVI float bflo(unsigned int u){ return __builtin_bit_cast(float, u << 16); }
DEVI float bfhi(unsigned int u){ return __builtin_bit_cast(float, u & 0xffff0000u); }

__global__ void k_zero(int* __restrict__ p, int n){
  int i = blockIdx.x*256 + threadIdx.x;
  if (i < n) p[i] = 0;
}

// ---- CSR build: hist+coarse-append scatter, scan, fine scatter, fused ----

// pass 1 (merged hist + coarse scatter): per chunk, LDS fine histogram ->
// global fine counts; coarse counts derived; coarse segments reserved by
// atomic-append into p1[c*CAP ...]; writes PACKED (src<<11)|(dst&2047).
__global__ __launch_bounds__(512) void kb_scat1h(const int* __restrict__ src,
    const int* __restrict__ dst, int* __restrict__ cntf, int* __restrict__ cntc,
    int* __restrict__ p1, int E, int NB, int NBC){
  __shared__ int hf[2048];
  __shared__ int baseSh[64];
  __shared__ int hc[64];
  int t = threadIdx.x;
  for (int i=t;i<NB;i+=512) hf[i]=0;
  __syncthreads();
  int base = blockIdx.x*SCH;
  int lim = base+SCH < E ? base+SCH : E;
  for (int i = base+t; i < lim; i += 512)
    atomicAdd(&hf[dst[i]>>8], 1);
  __syncthreads();
  if (t < NBC){
    int s2 = 0;
    int f0 = t*8;
    for (int j=0;j<8;j++){ int f=f0+j; if (f<NB) s2 += hf[f]; }
    baseSh[t] = s2 ? atomicAdd(&cntc[t], s2) : 0;
    hc[t] = 0;
  }
  for (int i=t;i<NB;i+=512)
    if (hf[i]) atomicAdd(&cntf[i], hf[i]);
  __syncthreads();
  for (int i = base+t; i < lim; i += 512){
    int d = dst[i];
    int b = d>>11;
    int r = atomicAdd(&hc[b], 1);
    p1[(size_t)b*CAP + baseSh[b] + r] = (src[i]<<11) | (d & 2047);
  }
}

// one block: fine prefix scan over cntf -> bOff (+bCur copy)
__global__ __launch_bounds__(256) void kb_scan(const int* __restrict__ cntf,
    int* __restrict__ bucketOff, int* __restrict__ bucketCur, int NB){
  __shared__ int sh[256];
  int t = threadIdx.x;
  int per = (NB+255)/256;
  int vals[8];
  int lsum = 0;
  for (int j=0;j<per;j++){
    int i = t*per+j;
    int v = (i<NB) ? cntf[i] : 0;
    vals[j]=v; lsum+=v;
  }
  sh[t]=lsum; __syncthreads();
  for (int off=1; off<256; off<<=1){
    int x = (t>=off) ? sh[t-off] : 0;
    __syncthreads();
    sh[t] += x;
    __syncthreads();
  }
  int run = sh[t]-lsum;
  for (int j=0;j<per;j++){
    int i = t*per+j;
    if (i<NB){ bucketOff[i]=run; bucketCur[i]=run; }
    run += vals[j];
  }
  if (t==255) bucketOff[NB]=run;
}

// pass 2: per-coarse-segment blocks (grid = NBC*8); bins packed p1 entries
// into fine buckets at global bCur offsets; writes (src<<8)|(dst&255).
__global__ __launch_bounds__(512) void kb_scat2(const int* __restrict__ p1,
    const int* __restrict__ cntc, int* __restrict__ cur,
    int* __restrict__ pk, int NB){
  __shared__ int h[8];
  __shared__ int baseSh[8];
  int t = threadIdx.x;
  int bc = blockIdx.x >> 3;
  int sub = blockIdx.x & 7;
  int s = bc*CAP;
  int e = s + cntc[bc];
  if (t < 8) h[t] = 0;
  __syncthreads();
  for (int i = s + sub*512 + t; i < e; i += 4096)
    atomicAdd(&h[(p1[i]>>8)&7], 1);
  __syncthreads();
  if (t < 8){
    int c2 = h[t];
    baseSh[t] = c2 ? atomicAdd(&cur[bc*8+t], c2) : 0;
    h[t] = 0;
  }
  __syncthreads();
  for (int i = s + sub*512 + t; i < e; i += 4096){
    int p = p1[i];
    int f = (p>>8)&7;
    int r = atomicAdd(&h[f], 1);
    int pos = baseSh[f] + r;
    pk[pos] = ((p>>11)<<8) | (p&255);
  }
}

// Pack row-major fp32 W[K][N] into MFMA B-fragment order:
// frag (ks, cf), lane l, elem j  <-  W[ks*32 + (l>>4)*8 + j][cf*16 + (l&15)]
DEVI void packW(const float* __restrict__ W, unsigned short* __restrict__ Wp,
                int idx, int N, int NF){
  int l = idx & 63;
  int frag = idx >> 6;
  int cf = frag % NF;
  int ks = frag / NF;
  int kbase = ks*32 + (l>>4)*8;
  int col = cf*16 + (l&15);
  unsigned short* dp = Wp + (size_t)idx*8;
  #pragma unroll
  for (int j=0;j<8;j++) dp[j] = f2bf(W[(size_t)(kbase+j)*N + col]);
}

// Fused per-bucket: count -> LDS scan -> rp/dinv -> rank & write csr -> cvt
// this bucket's x rows into xs (dinv-scaled bf16). Blocks >= NB pack W1/W2.
// pk entry = (src<<8)|(dst&255); csr entry = src<<8 (byte offset of xs row).
__global__ __launch_bounds__(256) void kb_fused(const int* __restrict__ pk,
    const int* __restrict__ bOff,
    int* __restrict__ rp, int* __restrict__ csr, float* __restrict__ dinv,
    const float2* __restrict__ x2, unsigned int* __restrict__ xb,
    const float* __restrict__ W1, unsigned short* __restrict__ W1p,
    const float* __restrict__ W2, unsigned short* __restrict__ W2p,
    int n, int NB, int E){
  int t = threadIdx.x;
  int b = blockIdx.x;
  if (b >= NB){
    int idx = (b-NB)*256 + t;
    if (idx < 4096) packW(W1, W1p, idx, 256, 16);        // K=128,N=256
    else            packW(W2, W2p, idx-4096, 128, 8);    // K=256,N=128
    return;
  }
  __shared__ int c[256];
  __shared__ int sh[256];
  __shared__ int cur[256];
  __shared__ float dv[256];
  int s = bOff[b], e2 = bOff[b+1];
  c[t]=0; __syncthreads();
  for (int i=s+t;i<e2;i+=256) atomicAdd(&c[pk[i]&255], 1);
  __syncthreads();
  int deg = c[t];
  sh[t]=deg; __syncthreads();
  for (int o=1;o<256;o<<=1){
    int x = (t>=o) ? sh[t-o] : 0;
    __syncthreads();
    sh[t]+=x;
    __syncthreads();
  }
  int excl = sh[t]-deg;
  int node = b*256+t;
  float dnv = rsqrtf((float)(deg+1));
  if (node<n){
    rp[node] = s + excl;
    dinv[node] = dnv;
  }
  if (b==NB-1 && t==0) rp[n] = E;
  cur[t] = s + excl;
  dv[t] = dnv;
  __syncthreads();
  for (int i=s+t;i<e2;i+=256){
    int p = pk[i];
    int r = atomicAdd(&cur[p&255], 1);
    csr[r] = p & (int)0xFFFFFF00u;
  }
  // cvt: xs[row] = bf16(dinv[row] * x[row]) for this bucket's rows
  int base_node = b*256;
  int rows = n - base_node; if (rows > 256) rows = 256;
  int j = t & 63;
  for (int rb = t>>6; rb < rows; rb += 4){
    int nd = base_node + rb;
    float d = dv[rb];
    float2 v = x2[(size_t)nd*64 + j];
    xb[(size_t)nd*64 + j] = packbf2(d*v.x, d*v.y);
  }
}

// Aggregate pre-scaled rows: out[d] = dinv[d] * (sum_{s in N(d)} xs[s] + xs[d])
// One wave per node. Lane l: quarter h=l>>4 handles edge sub-slot h, q=l&15
// owns features [8q, 8q+8) (16B uint4). Each gather instr covers 4 edges x 16B.
// Quarter partials reduced via shfl_xor(16/32). csr holds byte offsets.
#define ACC8(V) { a0+=bflo(V.x); a1+=bfhi(V.x); a2+=bflo(V.y); a3+=bfhi(V.y); \
                  a4+=bflo(V.z); a5+=bfhi(V.z); a6+=bflo(V.w); a7+=bfhi(V.w); }

template<bool FINAL>
__global__ __launch_bounds__(256) void k_agg(
    const unsigned int* __restrict__ xs, const int* __restrict__ rp,
    const int* __restrict__ csr, const float* __restrict__ dinv,
    const float* __restrict__ bias, unsigned int* __restrict__ outb,
    float* __restrict__ outf, int n){
  int node = blockIdx.x*4 + (threadIdx.x>>6);
  if (node >= n) return;
  int l = threadIdx.x & 63;
  int q = l & 15;
  int h = l >> 4;
  const char* xbase = (const char*)xs;
  float a0=0,a1=0,a2=0,a3=0,a4=0,a5=0,a6=0,a7=0;
  int e = rp[node], end = rp[node+1];
  int p = e;
  int nf = (end - e) >> 4;
  for (int blk=0; blk<nf; ++blk, p+=16){
    uint4 v[4];
    #pragma unroll
    for (int i=0;i<4;i++){
      int boff = csr[p + 4*i + h];
      v[i] = *(const uint4*)(xbase + (size_t)(unsigned)boff + q*16);
    }
    ACC8(v[0]); ACC8(v[1]); ACC8(v[2]); ACC8(v[3]);
  }
  int rem = end - p;
  if (rem >= 8){
    uint4 v[2];
    #pragma unroll
    for (int i=0;i<2;i++){
      int boff = csr[p + 4*i + h];
      v[i] = *(const uint4*)(xbase + (size_t)(unsigned)boff + q*16);
    }
    ACC8(v[0]); ACC8(v[1]);
    p += 8; rem -= 8;
  }
  if (rem > 0){
    uint4 v[2];
    #pragma unroll
    for (int i=0;i<2;i++){
      int ei = p + 4*i + h;
      int ec = ei < end-1 ? ei : end-1;
      int boff = csr[ec];
      uint4 t = *(const uint4*)(xbase + (size_t)(unsigned)boff + q*16);
      if (ei >= end){ t.x=0; t.y=0; t.z=0; t.w=0; }
      v[i] = t;
    }
    ACC8(v[0]); ACC8(v[1]);
  }
  a0 += __shfl_xor(a0,16); a0 += __shfl_xor(a0,32);
  a1 += __shfl_xor(a1,16); a1 += __shfl_xor(a1,32);
  a2 += __shfl_xor(a2,16); a2 += __shfl_xor(a2,32);
  a3 += __shfl_xor(a3,16); a3 += __shfl_xor(a3,32);
  a4 += __shfl_xor(a4,16); a4 += __shfl_xor(a4,32);
  a5 += __shfl_xor(a5,16); a5 += __shfl_xor(a5,32);
  a6 += __shfl_xor(a6,16); a6 += __shfl_xor(a6,32);
  a7 += __shfl_xor(a7,16); a7 += __shfl_xor(a7,32);
  // self term
  uint4 sv = *(const uint4*)(xbase + (size_t)node*256 + q*16);
  ACC8(sv);
  float dn = dinv[node];
  if constexpr (FINAL){
    if (h < 2){
      const float4 bb = *(const float4*)(bias + 8*q + 4*h);
      f32x4 r;
      r.x = (h ? a4 : a0)*dn + bb.x;
      r.y = (h ? a5 : a1)*dn + bb.y;
      r.z = (h ? a6 : a2)*dn + bb.z;
      r.w = (h ? a7 : a3)*dn + bb.w;
      __builtin_nontemporal_store(r, (f32x4*)(outf + (size_t)node*128 + 8*q + 4*h));
    }
  } else {
    if (h == 0){
      uint4 o;
      o.x = packbf2(a0*dn, a1*dn);
      o.y = packbf2(a2*dn, a3*dn);
      o.z = packbf2(a4*dn, a5*dn);
      o.w = packbf2(a6*dn, a7*dn);
      *(uint4*)((char*)outb + (size_t)node*256 + q*16) = o;
    }
  }
}

// LDS addr for H1 tile [64 rows][256 cols bf16], 16B-granule XOR swizzle.
DEVI int ldsaddr(int row, int colg /*granule = col>>3*/){
  int gs = (colg & ~7) | ((colg & 7) ^ (row & 7));
  return row*512 + gs*16;
}

// Fused MLP: per 64-row tile,
// phase 1: H1tile = relu(AX @ W1p + b1) -> LDS (bf16, swizzled)
// phase 2: T = dinv .* (H1tile @ W2p)   -> global (bf16)
__global__ __launch_bounds__(256) void k_mlp(
    const unsigned short* __restrict__ A, const unsigned short* __restrict__ W1p,
    const float* __restrict__ b1, const unsigned short* __restrict__ W2p,
    const float* __restrict__ dinv, unsigned short* __restrict__ T, int M){
  __shared__ unsigned char At[64*512];
  int l = threadIdx.x & 63;
  int w = threadIdx.x >> 6;
  int r0 = blockIdx.x*64;
  int lr = l & 15, lg = l >> 4;
  int c0 = w*64;                      // phase-1 col span [c0, c0+64)
  // ---- phase 1: GEMM1 64x256, K=128 ----
  {
    f32x4 acc[4][4];
    #pragma unroll
    for (int i=0;i<4;i++)
      #pragma unroll
      for (int j=0;j<4;j++)
        acc[i][j] = f32x4{0.f,0.f,0.f,0.f};
    #pragma unroll
    for (int ks=0; ks<4; ++ks){
      bf16x8 a[4], b[4];
      #pragma unroll
      for (int ar=0;ar<4;ar++){
        int row = r0 + ar*16 + lr;
        if (row > M-1) row = M-1;
        const uint4* p = (const uint4*)(A + (size_t)row*128 + ks*32 + lg*8);
        union { uint4 u; bf16x8 v; } t; t.u = *p; a[ar] = t.v;
      }
      #pragma unroll
      for (int cb=0;cb<4;cb++){
        int cf = (c0>>4) + cb;
        const uint4* p = (const uint4*)(W1p + ((size_t)(ks*16 + cf)*64 + l)*8);
        union { uint4 u; bf16x8 v; } t; t.u = *p; b[cb] = t.v;
      }
      #pragma unroll
      for (int ar=0;ar<4;ar++)
        #pragma unroll
        for (int cb=0;cb<4;cb++)
          acc[ar][cb] = __builtin_amdgcn_mfma_f32_16x16x32_bf16(a[ar], b[cb], acc[ar][cb], 0, 0, 0);
    }
    // epilogue: bias+relu -> LDS bf16 (swizzled)
    #pragma unroll
    for (int ar=0;ar<4;ar++){
      #pragma unroll
      for (int i=0;i<4;i++){
        int row = ar*16 + lg*4 + i;
        #pragma unroll
        for (int cb=0;cb<4;cb++){
          int col = c0 + cb*16 + lr;
          float v = acc[ar][cb][i] + b1[col];
          v = fmaxf(v, 0.f);
          *(unsigned short*)(At + ldsaddr(row, col>>3) + (col&7)*2) = f2bf(v);
        }
      }
    }
  }
  __syncthreads();
  // ---- phase 2: GEMM2 64x128, K=256, A from LDS ----
  {
    f32x4 acc[4][2];
    #pragma unroll
    for (int i=0;i<4;i++){
      acc[i][0] = f32x4{0.f,0.f,0.f,0.f};
      acc[i][1] = f32x4{0.f,0.f,0.f,0.f};
    }
    #pragma unroll
    for (int ks=0; ks<8; ++ks){
      bf16x8 a[4], b[2];
      #pragma unroll
      for (int ar=0;ar<4;ar++){
        int row = ar*16 + lr;
        union { uint4 u; bf16x8 v; } t;
        t.u = *(const uint4*)(At + ldsaddr(row, ks*4 + lg));
        a[ar] = t.v;
      }
      #pragma unroll
      for (int cb=0;cb<2;cb++){
        int cf = w*2 + cb;
        const uint4* p = (const uint4*)(W2p + ((size_t)(ks*8 + cf)*64 + l)*8);
        union { uint4 u; bf16x8 v; } t; t.u = *p; b[cb] = t.v;
      }
      #pragma unroll
      for (int ar=0;ar<4;ar++){
        acc[ar][0] = __builtin_amdgcn_mfma_f32_16x16x32_bf16(a[ar], b[0], acc[ar][0], 0, 0, 0);
        acc[ar][1] = __builtin_amdgcn_mfma_f32_16x16x32_bf16(a[ar], b[1], acc[ar][1], 0, 0, 0);
      }
    }
    #pragma unroll
    for (int ar=0;ar<4;ar++){
      #pragma unroll
      for (int i=0;i<4;i++){
        int row = r0 + ar*16 + lg*4 + i;
        if (row < M){
          float rs = dinv[row];
          #pragma unroll
          for (int cb=0;cb<2;cb++){
            int col = w*32 + cb*16 + lr;
            T[(size_t)row*128 + col] = f2bf(acc[ar][cb][i] * rs);
          }
        }
      }
    }
  }
}

extern "C" void kernel_launch(void* const* d_in, const int* in_sizes, int n_in,
                              void* d_out, int out_size, void* d_ws, size_t ws_size,
                              hipStream_t stream){
  const float* x  = (const float*)d_in[0];
  const int*   ei = (const int*)d_in[1];
  const float* W1 = (const float*)d_in[2];
  const float* b1 = (const float*)d_in[3];
  const float* W2 = (const float*)d_in[4];
  const float* b2 = (const float*)d_in[5];
  const int IN_F = 128;
  int n = in_sizes[0] / IN_F;      // 100000
  int E = in_sizes[1] / 2;         // 1600000
  const int* srcI = ei;
  const int* dstI = ei + E;
  const int NB  = (n+255)>>8;      // fine buckets (256 nodes)
  const int NBC = (n+2047)>>11;    // coarse buckets (2048 nodes)

  char* ws = (char*)d_ws;
  size_t off = 0;
  auto alloc = [&](size_t bytes)->char*{
    char* p = ws + off; off += (bytes + 255) & ~(size_t)255; return p;
  };
  int*   rp    = (int*)  alloc(((size_t)n+1)*4);
  float* dinv  = (float*)alloc((size_t)n*4);
  int*   cntf  = (int*)  alloc(((size_t)NB+NBC)*4);
  int*   cntc  = cntf + NB;
  int*   bOff  = (int*)  alloc(((size_t)NB+1)*4);
  int*   bCur  = (int*)  alloc((size_t)NB*4);
  unsigned short* W1p = (unsigned short*)alloc((size_t)128*256*2);
  unsigned short* W2p = (unsigned short*)alloc((size_t)256*128*2);
  int*   csr   = (int*)  alloc((size_t)E*4);
  unsigned int* xb = (unsigned int*)alloc((size_t)n*64*4);  // xs; reused as T
  unsigned int* AX = (unsigned int*)alloc((size_t)n*64*4);
  int*   p1    = (int*)  alloc((size_t)NBC*CAP*4);
  int*   pk    = (int*)  alloc((size_t)E*4);

  int NSC = (E + SCH - 1)/SCH;

  k_zero<<<(NB+NBC+255)/256,256,0,stream>>>(cntf, NB+NBC);
  kb_scat1h<<<NSC,512,0,stream>>>(srcI, dstI, cntf, cntc, p1, E, NB, NBC);
  kb_scan<<<1,256,0,stream>>>(cntf, bOff, bCur, NB);
  kb_scat2<<<NBC*8,512,0,stream>>>(p1, cntc, bCur, pk, NB);
  kb_fused<<<NB+32,256,0,stream>>>(pk, bOff, rp, csr, dinv,
                                   (const float2*)x, xb, W1, W1p, W2, W2p, n, NB, E);
  // layer 1 agg: AX = A_hat-gather of xs
  k_agg<false><<<(n+3)/4,256,0,stream>>>(xb, rp, csr, dinv, nullptr, AX, nullptr, n);
  // fused MLP: T = dinv .* (relu(AX @ W1 + b1) @ W2)
  unsigned int* T = xb;
  k_mlp<<<(n+63)/64,256,0,stream>>>((const unsigned short*)AX, W1p, b1, W2p,
                                    dinv, (unsigned short*)T, n);
  // layer 2 agg: out = dinv .* gather(T) + b2
  k_agg<true><<<(n+3)/4,256,0,stream>>>(T, rp, csr, dinv, b2, nullptr, (float*)d_out, n);
}